// Round 7
// baseline (45.447 us; speedup 1.0000x reference)
//
#include <hip/hip_runtime.h>

// NF4 quantize->dequantize (blocksize 512), STE forward replicated exactly.
// x: (4096, 8192) float32. One 64-lane wave per 512-elem quant block.
//
// Correctness model M7: ref = the XLA-GPU expected output. XLA rewrites
// division-by-broadcast-scalar into multiply-by-reciprocal:
//     r  = fl32(1.0 / scale)        (CR f32 divide)
//     xn = fl32(v * r)              (CR f32 multiply)  <- ONE EXTRA ROUNDING vs /
//     idx = #{ j : xn > MID32[j] }  (searchsorted side='left', f32 compares)
//     xhat = fl32(NF4[idx] * absmax)
//     out  = fl32(fl32(xhat + v) - v)   (straight-through-estimator arithmetic)
// Evidence: all six CR-divide / f64 emulations (R1-R6) failed with few-flip
// signatures whose worst elements side with the REAL quotient at one element
// (e1, 13<->14, am~3.46) but with the CR-f32 quotient at another (e2, 7<->8,
// am~4.69) — impossible for any single-rounding model; exactly what a
// twice-rounded reciprocal-multiply quotient produces.

#define QBLOCK 512

__global__ __launch_bounds__(256) void nf4_qdq_kernel(
    const float* __restrict__ x, float* __restrict__ out, long long n)
{
    const float nf4f[16] = {
        -1.0f, -0.6961928009986877f, -0.5250730514526367f, -0.39491748809814453f,
        -0.28444138169288635f, -0.18477343022823334f, -0.09105003625154495f, 0.0f,
        0.07958029955625534f, 0.16093020141124725f, 0.24611230194568634f,
        0.33791524171829224f, 0.4407098591327667f, 0.5626170039176941f,
        0.7229568362236023f, 1.0f};

    // f32 decision boundaries, computed as the reference does
    float mid32[15];
    #pragma unroll
    for (int j = 0; j < 15; ++j)
        mid32[j] = (nf4f[j] + nf4f[j + 1]) * 0.5f;

    const long long gtid = (long long)blockIdx.x * blockDim.x + threadIdx.x;
    const long long wave = gtid >> 6;               // global wave id = quant-block id
    const int lane = (int)(threadIdx.x & 63);
    const long long base = wave * (long long)QBLOCK;
    if (base >= n) return;

    const float4* __restrict__ xv = (const float4*)(x + base);
    float4 a = xv[lane];        // elems [lane*4 .. lane*4+3]
    float4 b = xv[lane + 64];   // elems [256+lane*4 ..]

    float m = fmaxf(fmaxf(fabsf(a.x), fabsf(a.y)), fmaxf(fabsf(a.z), fabsf(a.w)));
    m = fmaxf(m, fmaxf(fmaxf(fabsf(b.x), fabsf(b.y)), fmaxf(fabsf(b.z), fabsf(b.w))));

    // 64-lane butterfly max reduction
    #pragma unroll
    for (int off = 32; off > 0; off >>= 1)
        m = fmaxf(m, __shfl_xor(m, off, 64));

    const float absmax = m;
    const float scale = (absmax == 0.0f) ? 1.0f : absmax;
    // XLA-style hoisted reciprocal: ONE correctly-rounded f32 divide per block.
    // (No fast-math in harness flags -> this is the IEEE divide, not rcp.)
    const float rinv = 1.0f / scale;

    // qdq + STE, all f32, matching XLA op-for-op
    auto qdq = [&](float v) -> float {
        const float q = v * rinv;           // twice-rounded quotient (CR mul)
        float r = nf4f[0];
        #pragma unroll
        for (int j = 0; j < 15; ++j)
            r = (q > mid32[j]) ? nf4f[j + 1] : r;   // side='left': ties go DOWN
        const float xhat = r * absmax;
        return (xhat + v) - v;              // STE forward arithmetic, exact replica
    };

    float4 oa, ob;
    oa.x = qdq(a.x); oa.y = qdq(a.y); oa.z = qdq(a.z); oa.w = qdq(a.w);
    ob.x = qdq(b.x); ob.y = qdq(b.y); ob.z = qdq(b.z); ob.w = qdq(b.w);

    float4* __restrict__ ov = (float4*)(out + base);
    ov[lane] = oa;
    ov[lane + 64] = ob;
}

extern "C" void kernel_launch(void* const* d_in, const int* in_sizes, int n_in,
                              void* d_out, int out_size, void* d_ws, size_t ws_size,
                              hipStream_t stream)
{
    const float* x = (const float*)d_in[0];
    float* out = (float*)d_out;
    const long long n = (long long)in_sizes[0];   // 4096*8192, divisible by 512

    const long long threads_needed = n / 8;       // 8 elems per thread
    const int block = 256;
    const int grid = (int)((threads_needed + block - 1) / block);

    nf4_qdq_kernel<<<grid, block, 0, stream>>>(x, out, n);
}